// Round 7
// baseline (27.078 us; speedup 1.0000x reference)
//
#include <hip/hip_runtime.h>

// Exponential concordance loss — single kernel, O(1) deterministic combine:
// loss_sum = sum over (a,b) with dur[b] < dur[a] and ev[b]==1 of exp(p[a]-p[b])
//          = sum_a epos[a] * sum_{b: dur_b<dur_a} w[b],  w[b]=ev[b]?exp(-p[b]):0
// out = loss_sum / num_pairs
//
// Combine: block partial (double) -> fixed-point 2^20 int64 -> device-scope
// integer atomicAdd (commutative => bit-deterministic regardless of schedule).
// Count likewise. Thread0 then drains vmcnt and takes a relaxed ticket; the
// last block's thread0 alone reads the two totals, divides, stores out, and
// resets the module-scope globals (load-time zeroed; never touched by the
// harness's 0xAA poison; reset each call => graph replays stay correct).

#define TPB 256
#define NB 8          // columns per thread (register-resident)
#define ACHUNK 64     // rows staged in LDS per block
#define FIXSCALE 1048576.0   // 2^20

__device__ unsigned long long g_sum = 0;   // fixed-point loss_sum
__device__ unsigned long long g_cnt = 0;   // num_pairs
__device__ int g_ticket = 0;

__global__ void __launch_bounds__(TPB) pair_single(const float* __restrict__ preds,
                                                   const float2* __restrict__ targets, // (dur, ev)
                                                   float* __restrict__ out,
                                                   int n, int nblocks) {
    const int colGroups = n / (TPB * NB);          // 8192/2048 = 4
    const int cg = blockIdx.x % colGroups;
    const int ac = blockIdx.x / colGroups;
    const int base_a = ac * ACHUNK;
    const int base_b = cg * TPB * NB + threadIdx.x;

    __shared__ float2 sa[ACHUNK];                  // (dur_a, epos_a)
    if (threadIdx.x < ACHUNK) {
        int a = base_a + threadIdx.x;
        float2 t = targets[a];
        sa[threadIdx.x] = make_float2(t.x, __expf(preds[a]));
    }

    float db[NB], wb[NB];
#pragma unroll
    for (int k = 0; k < NB; ++k) {
        int b = base_b + k * TPB;                  // coalesced
        float2 t = targets[b];
        float  p = preds[b];
        db[k] = t.x;
        wb[k] = (t.y == 1.0f) ? __expf(-p) : 0.0f;
    }
    __syncthreads();

    float sum[NB];
    int   cnt[NB];
#pragma unroll
    for (int k = 0; k < NB; ++k) { sum[k] = 0.0f; cnt[k] = 0; }

#pragma unroll 8
    for (int i = 0; i < ACHUNK; ++i) {
        float2 a = sa[i];                          // uniform address -> broadcast
#pragma unroll
        for (int k = 0; k < NB; ++k) {
            bool v = db[k] < a.x;
            sum[k] += v ? a.y : 0.0f;
            cnt[k] += v;
        }
    }

    float lsum = 0.0f;
    int   lcnt = 0;
#pragma unroll
    for (int k = 0; k < NB; ++k) {
        if (wb[k] > 0.0f) {                        // ev[b]==1  <=>  w_b>0
            lsum += wb[k] * sum[k];
            lcnt += cnt[k];
        }
    }

    // ---- block reduction of (lsum, lcnt) ----
    __shared__ float ssum[TPB];
    __shared__ int   scnt[TPB];
    ssum[threadIdx.x] = lsum;
    scnt[threadIdx.x] = lcnt;
    __syncthreads();
    for (int s = TPB / 2; s > 0; s >>= 1) {
        if (threadIdx.x < s) {
            ssum[threadIdx.x] += ssum[threadIdx.x + s];
            scnt[threadIdx.x] += scnt[threadIdx.x + s];
        }
        __syncthreads();
    }

    // ---- O(1) combine: fixed-point integer atomics, then ticket ----
    if (threadIdx.x == 0) {
        unsigned long long q = (unsigned long long)__double2ll_rn((double)ssum[0] * FIXSCALE);
        atomicAdd(&g_sum, q);                              // device scope, deterministic
        atomicAdd(&g_cnt, (unsigned long long)scnt[0]);
        asm volatile("s_waitcnt vmcnt(0)" ::: "memory");   // adds ack'd at coherence point
        int t = __hip_atomic_fetch_add(&g_ticket, 1,
                                       __ATOMIC_RELAXED, __HIP_MEMORY_SCOPE_AGENT);
        if (t == nblocks - 1) {
            unsigned long long s = __hip_atomic_load(&g_sum, __ATOMIC_RELAXED, __HIP_MEMORY_SCOPE_AGENT);
            unsigned long long c = __hip_atomic_load(&g_cnt, __ATOMIC_RELAXED, __HIP_MEMORY_SCOPE_AGENT);
            out[0] = (c > 0) ? (float)(((double)s / FIXSCALE) / (double)c) : 0.0f;
            // reset globals for the next call (all blocks have contributed)
            __hip_atomic_store(&g_sum, 0ULL, __ATOMIC_RELAXED, __HIP_MEMORY_SCOPE_AGENT);
            __hip_atomic_store(&g_cnt, 0ULL, __ATOMIC_RELAXED, __HIP_MEMORY_SCOPE_AGENT);
            __hip_atomic_store(&g_ticket, 0, __ATOMIC_RELAXED, __HIP_MEMORY_SCOPE_AGENT);
        }
    }
}

extern "C" void kernel_launch(void* const* d_in, const int* in_sizes, int n_in,
                              void* d_out, int out_size, void* d_ws, size_t ws_size,
                              hipStream_t stream) {
    const float*  preds   = (const float*)d_in[0];
    const float2* targets = (const float2*)d_in[1];   // [n] of (dur, ev)
    float* out = (float*)d_out;
    int n = in_sizes[0];   // 8192

    int colGroups = n / (TPB * NB);                // 4
    int aChunks   = n / ACHUNK;                    // 128
    int nblocks   = colGroups * aChunks;           // 512

    pair_single<<<nblocks, TPB, 0, stream>>>(preds, targets, out, n, nblocks);
}

// Round 8
// 13.273 us; speedup vs baseline: 2.0400x; 2.0400x over previous
//
#include <hip/hip_runtime.h>

// Exponential concordance loss — sorted-chunk + suffix-sum + binary search:
// loss_sum = sum over (a,b) with dur[b] < dur[a] and ev[b]==1 of exp(p[a]-p[b])
//          = sum_b w[b] * S_b,  w[b]=ev[b]?exp(-p[b]):0,
//   where S_b = sum of exp(p[a]) over rows a with dur_a > dur_b.
// Per 64-row chunk: wave0 bitonic-sorts (dur, epos) by dur across 64 lanes
// (register shuffles), suffix-scans epos, publishes sdur[64]/ssuf[65] to LDS.
// Each thread then resolves its NB columns with a 6-step binary search + one
// suffix lookup instead of 64 compare-adds. Two-kernel structure (R3): block
// partials -> tiny finalize kernel (in-kernel grid sync proved slower, R4-R7).

#define TPB 256
#define NB 8          // columns per thread
#define ACHUNK 64     // rows per chunk == one wave

__global__ void __launch_bounds__(TPB) pair_fused(const float* __restrict__ preds,
                                                  const float2* __restrict__ targets, // (dur, ev)
                                                  float* __restrict__ psum,
                                                  int* __restrict__ pcnt,
                                                  int n) {
    const int colGroups = n / (TPB * NB);          // 8192/2048 = 4
    const int cg = blockIdx.x % colGroups;
    const int ac = blockIdx.x / colGroups;
    const int base_a = ac * ACHUNK;
    const int base_b = cg * TPB * NB + threadIdx.x;

    __shared__ float sdur[ACHUNK];     // sorted durations (ascending)
    __shared__ float ssuf[ACHUNK + 1]; // inclusive suffix sums of epos; ssuf[64]=0

    // ---- wave 0: load chunk, bitonic sort by dur, suffix-scan epos ----
    if (threadIdx.x < 64) {
        const int lane = threadIdx.x;
        float2 t  = targets[base_a + lane];
        float dur = t.x;
        float ep  = __expf(preds[base_a + lane]);
#pragma unroll
        for (int k = 2; k <= 64; k <<= 1) {
#pragma unroll
            for (int j = k >> 1; j > 0; j >>= 1) {
                float od = __shfl_xor(dur, j, 64);
                float oe = __shfl_xor(ep,  j, 64);
                bool lower    = (lane & j) == 0;
                bool asc      = (lane & k) == 0;   // k=64: all ascending
                bool take_min = (lower == asc);
                bool take_other = take_min ? (od < dur) : (od > dur);
                dur = take_other ? od : dur;
                ep  = take_other ? oe : ep;
            }
        }
        // inclusive suffix sum across lanes (Hillis-Steele, 6 steps)
        float suf = ep;
#pragma unroll
        for (int d = 1; d < 64; d <<= 1) {
            float v = __shfl_down(suf, d, 64);
            suf += (lane + d < 64) ? v : 0.0f;
        }
        sdur[lane] = dur;
        ssuf[lane] = suf;
        if (lane == 0) ssuf[64] = 0.0f;
    }

    // ---- all threads: load columns (coalesced) ----
    float qb[NB], wb[NB];
#pragma unroll
    for (int k = 0; k < NB; ++k) {
        int b = base_b + k * TPB;
        float2 t = targets[b];
        float  p = preds[b];
        qb[k] = t.x;
        wb[k] = (t.y == 1.0f) ? __expf(-p) : 0.0f;
    }
    __syncthreads();

    // ---- per column: upper-bound binary search + suffix lookup ----
    float lsum = 0.0f;
    int   lcnt = 0;
#pragma unroll
    for (int k = 0; k < NB; ++k) {
        int pos = 0;                               // will be count of dur_a <= q
#pragma unroll
        for (int s = 32; s > 0; s >>= 1)
            pos += (sdur[pos + s - 1] <= qb[k]) ? s : 0;
        if (wb[k] > 0.0f) {                        // ev[b]==1 <=> w_b>0
            lsum += wb[k] * ssuf[pos];
            lcnt += (ACHUNK - pos);
        }
    }

    // ---- block reduction of (lsum, lcnt) ----
    __shared__ float ssum[TPB];
    __shared__ int   scnt[TPB];
    ssum[threadIdx.x] = lsum;
    scnt[threadIdx.x] = lcnt;
    __syncthreads();
    for (int s = TPB / 2; s > 0; s >>= 1) {
        if (threadIdx.x < s) {
            ssum[threadIdx.x] += ssum[threadIdx.x + s];
            scnt[threadIdx.x] += scnt[threadIdx.x + s];
        }
        __syncthreads();
    }
    if (threadIdx.x == 0) {
        psum[blockIdx.x] = ssum[0];
        pcnt[blockIdx.x] = scnt[0];
    }
}

__global__ void __launch_bounds__(TPB) finalize_kernel(const float* __restrict__ psum,
                                                       const int* __restrict__ pcnt,
                                                       float* __restrict__ out,
                                                       int nb) {
    __shared__ double    ds[TPB];
    __shared__ long long dc[TPB];
    double    ls = 0.0;
    long long lc = 0;
    for (int i = threadIdx.x; i < nb; i += TPB) {
        ls += (double)psum[i];
        lc += (long long)pcnt[i];
    }
    ds[threadIdx.x] = ls;
    dc[threadIdx.x] = lc;
    __syncthreads();
    for (int s = TPB / 2; s > 0; s >>= 1) {
        if (threadIdx.x < s) {
            ds[threadIdx.x] += ds[threadIdx.x + s];
            dc[threadIdx.x] += dc[threadIdx.x + s];
        }
        __syncthreads();
    }
    if (threadIdx.x == 0) {
        out[0] = (dc[0] > 0) ? (float)(ds[0] / (double)dc[0]) : 0.0f;
    }
}

extern "C" void kernel_launch(void* const* d_in, const int* in_sizes, int n_in,
                              void* d_out, int out_size, void* d_ws, size_t ws_size,
                              hipStream_t stream) {
    const float*  preds   = (const float*)d_in[0];
    const float2* targets = (const float2*)d_in[1];   // [n] of (dur, ev)
    float* out = (float*)d_out;
    int n = in_sizes[0];   // 8192

    int colGroups = n / (TPB * NB);                // 4
    int aChunks   = n / ACHUNK;                    // 128
    int nblocks   = colGroups * aChunks;           // 512

    // ws layout: psum[nblocks] f32, pcnt[nblocks] i32
    float* psum = (float*)d_ws;
    int*   pcnt = (int*)(psum + nblocks);

    pair_fused<<<nblocks, TPB, 0, stream>>>(preds, targets, psum, pcnt, n);
    finalize_kernel<<<1, TPB, 0, stream>>>(psum, pcnt, out, nblocks);
}